// Round 4
// baseline (169.870 us; speedup 1.0000x reference)
//
#include <hip/hip_runtime.h>

// SSIM fused, v4: both separable conv passes on MFMA (v_mfma_f32_16x16x32_bf16).
// Conv-as-band-matmul: D[m][n] = sum_k A[m][k] * B[k][n] with a constant band
// matrix Band[i][k] = g[k-i] (zero outside 0<=k-i<=10).
//   stage : raw pixels -> 4 bf16 quantity planes {x1, x2, x1^2+x2^2, x1*x2},
//           row-major in LDS (col/row shift +5, margins zeroed for NaN-safety).
//   h-pass: A = raw rows (ds_read_b128), B = Band (registers). 24 mfma / block.
//           D (C-layout: col=lane&15, row=quad*4+reg) writes col-major H planes
//           as ds_write_b64 -- exactly the v-pass B-fragment layout. No transpose.
//   v-pass: A = Band, B = H cols (ds_read_b128). 16 mfma / block. SSIM math on
//           the fp32 accumulators, block reduce -> per-block partial.
// Band frag content is identical for A-role and B-role (both: 16-dim = lane&15,
// k = quad*8+j) -> one register fragment serves both passes.
// bf16 inputs / fp32 accum: per-pixel error unbiased, output is mean of 12.6M px.

#define IMG 512
#define NPIX (16LL * 3 * 512 * 512)
#define NBLK (16 * 16 * 48)
#define RP 56   /* raw plane row pitch (shorts): mult of 8 -> 16B-aligned b128, 112B = 28dw -> 2-way banks (free) */
#define HP 56   /* H plane col pitch (shorts), same properties */

typedef short v8s __attribute__((ext_vector_type(8)));   // 8 x bf16 (4 VGPRs)
typedef float v4f __attribute__((ext_vector_type(4)));   // MFMA accumulator

__device__ __forceinline__ unsigned f2bf(float f) {      // fp32 -> bf16 (RNE)
    unsigned u = __float_as_uint(f);
    return (u + 0x7FFFu + ((u >> 16) & 1u)) >> 16;
}
__device__ __forceinline__ int packbf(float lo, float hi) {
    return (int)((f2bf(hi) << 16) | f2bf(lo));
}

__global__ __launch_bounds__(256, 4) void ssim_kernel(
    const float* __restrict__ img1,
    const float* __restrict__ img2,
    const float* __restrict__ win,
    float* __restrict__ partial)
{
    __shared__ __align__(16) short raw [4][48][RP];  // 21504 B, row-major
    __shared__ __align__(16) short hbuf[4][32][HP];  // 14336 B, col-major ([col][row])
    __shared__ float sg[12];
    __shared__ float red[4];

    const int tid  = threadIdx.x;
    const int lane = tid & 63;
    const int wave = tid >> 6;
    const int lm   = lane & 15;   // 16-dim index for A/B/D fragments
    const int quad = lane >> 4;

    const int bx = blockIdx.x, by = blockIdx.y, z = blockIdx.z;
    const int tx0 = bx * 32, ty0 = by * 32;

    // 1D gaussian from 2D window; sg[11] = 0 sentinel for band clamping.
    if (tid < 12) sg[tid] = (tid < 11) ? win[55 + tid] * rsqrtf(win[60]) : 0.f;

    // Zero all raw planes (margins must be finite: garbage*0 in MFMA can be NaN).
    {
        float4 zf4; zf4.x = zf4.y = zf4.z = zf4.w = 0.f;
        float4* rz = (float4*)&raw[0][0][0];
        const int n16 = (int)(sizeof(raw) / 16);       // 1344
        for (int i = tid; i < n16; i += 256) rz[i] = zf4;
    }
    __syncthreads();

    // Band fragment: value g[k - i], i = lane&15, k = quad*8 + j.
    v8s band;
    #pragma unroll
    for (int j = 0; j < 8; ++j) {
        int t  = quad * 8 + j - lm;
        int tc = ((unsigned)t > 10u) ? 11 : t;         // sg[11] == 0
        band[j] = (short)f2bf(sg[tc]);
    }

    // ---- stage: 42 rows x 21 col-pairs of bf16 quantity pixels ----
    {
        const size_t zoff = (size_t)z * IMG * IMG;
        const float* __restrict__ p1 = img1 + zoff;
        const float* __restrict__ p2 = img2 + zoff;
        const bool edge = (bx == 0) | (bx == 15) | (by == 0) | (by == 15);

        for (int idx = tid; idx < 42 * 21; idx += 256) {
            const int ri = idx / 21;            // raw row 0..41
            const int p  = idx - ri * 21;       // col pair 0..20
            const int rc = 2 * p;               // raw col (even -> b32 write)
            const int gr = ty0 - 5 + ri;
            const int gc = tx0 - 5 + rc;
            float a0, a1, b0, b1;
            if (!edge) {
                const size_t o = (size_t)gr * IMG + gc;
                a0 = p1[o]; a1 = p1[o + 1];
                b0 = p2[o]; b1 = p2[o + 1];
            } else {
                a0 = a1 = b0 = b1 = 0.f;
                if ((unsigned)gr < IMG) {
                    const size_t ro = (size_t)gr * IMG;
                    if ((unsigned)gc < IMG)       { a0 = p1[ro + gc];     b0 = p2[ro + gc]; }
                    if ((unsigned)(gc + 1) < IMG) { a1 = p1[ro + gc + 1]; b1 = p2[ro + gc + 1]; }
                }
            }
            *(int*)&raw[0][ri][rc] = packbf(a0, a1);
            *(int*)&raw[1][ri][rc] = packbf(b0, b1);
            *(int*)&raw[2][ri][rc] = packbf(fmaf(a0, a0, b0 * b0), fmaf(a1, a1, b1 * b1));
            *(int*)&raw[3][ri][rc] = packbf(a0 * b0, a1 * b1);
        }
    }
    __syncthreads();

    // ---- h-pass: 24 mfma (3 row-tiles x 2 col-tiles x 4 planes), 6 per wave ----
    const v4f zacc = {0.f, 0.f, 0.f, 0.f};
    #pragma unroll
    for (int i = 0; i < 6; ++i) {
        const int id    = wave * 6 + i;
        const int plane = id & 3;
        const int s     = id >> 2;                       // 0..5 spatial
        const int r0    = (s < 3 ? s : s - 3) * 16;      // raw row tile
        const int c0    = (s < 3 ? 0 : 16);              // out col tile
        // A frag: raw[plane][r0+lm][c0 + quad*8 + j]  (16B-aligned b128)
        const v8s a = *(const v8s*)&raw[plane][r0 + lm][c0 + quad * 8];
        const v4f acc = __builtin_amdgcn_mfma_f32_16x16x32_bf16(a, band, zacc, 0, 0, 0);
        // D: col n=lm (out col), rows r0 + quad*4 + reg -> col-major H, b64 write.
        int2 w2;
        w2.x = packbf(acc[0], acc[1]);
        w2.y = packbf(acc[2], acc[3]);
        *(int2*)&hbuf[plane][c0 + lm][r0 + quad * 4] = w2;
    }
    __syncthreads();

    // ---- v-pass: wave -> one 16x16 out tile, 4 plane-mfmas ----
    const int r0v = (wave & 1) * 16;
    const int c0v = (wave >> 1) * 16;
    v4f acc[4];
    #pragma unroll
    for (int p = 0; p < 4; ++p) {
        // B frag: hbuf[p][c0v+lm][r0v + quad*8 + j]  (16B-aligned b128)
        const v8s hf = *(const v8s*)&hbuf[p][c0v + lm][r0v + quad * 8];
        acc[p] = __builtin_amdgcn_mfma_f32_16x16x32_bf16(band, hf, zacc, 0, 0, 0);
    }

    const float C1c = 1e-4f;   // 0.01^2
    const float C2c = 9e-4f;   // 0.03^2
    float vsum = 0.f;
    #pragma unroll
    for (int r = 0; r < 4; ++r) {
        const float m1 = acc[0][r], m2 = acc[1][r];
        const float es = acc[2][r], ex = acc[3][r];
        const float m1s = m1 * m1, m2s = m2 * m2, m12 = m1 * m2;
        const float sig = es - m1s - m2s;               // sig1_sq + sig2_sq
        const float s12 = ex - m12;
        const float num = (2.f * m12 + C1c) * (2.f * s12 + C2c);
        const float den = (m1s + m2s + C1c) * (sig + C2c);
        vsum += num * __builtin_amdgcn_rcpf(den);
    }

    // ---- block reduction -> per-block partial ----
    #pragma unroll
    for (int off = 32; off > 0; off >>= 1)
        vsum += __shfl_down(vsum, off, 64);
    if (lane == 0) red[wave] = vsum;
    __syncthreads();
    if (tid == 0) {
        const int bidx = (z * (int)gridDim.y + by) * (int)gridDim.x + bx;
        partial[bidx] = red[0] + red[1] + red[2] + red[3];
    }
}

__global__ __launch_bounds__(256) void finalize_kernel(
    const float* __restrict__ partial, float* __restrict__ out)
{
    __shared__ float red[4];
    const float4* p4 = (const float4*)partial;
    float s = 0.f;
    for (int i = threadIdx.x; i < NBLK / 4; i += 256) {
        float4 t = p4[i];
        s += (t.x + t.y) + (t.z + t.w);
    }
    #pragma unroll
    for (int off = 32; off > 0; off >>= 1)
        s += __shfl_down(s, off, 64);
    if ((threadIdx.x & 63) == 0) red[threadIdx.x >> 6] = s;
    __syncthreads();
    if (threadIdx.x == 0)
        out[0] = 1.0f - (red[0] + red[1] + red[2] + red[3]) / (float)NPIX;
}

extern "C" void kernel_launch(void* const* d_in, const int* in_sizes, int n_in,
                              void* d_out, int out_size, void* d_ws, size_t ws_size,
                              hipStream_t stream) {
    const float* img1 = (const float*)d_in[0];
    const float* img2 = (const float*)d_in[1];
    const float* win  = (const float*)d_in[2];
    float* partialb = (float*)d_ws;  // NBLK floats; every slot written each call

    dim3 grid(IMG / 32, IMG / 32, 48);
    ssim_kernel<<<grid, dim3(256), 0, stream>>>(img1, img2, win, partialb);
    finalize_kernel<<<1, dim3(256), 0, stream>>>(partialb, (float*)d_out);
}

// Round 5
// 151.255 us; speedup vs baseline: 1.1231x; 1.1231x over previous
//
#include <hip/hip_runtime.h>

// SSIM fused, v5: MFMA band-matmul conv (v4 structure) + cheap staging.
//   - bf16 pack via v_cvt_pk_bf16_f32 (__builtin_convertvector fptrunc f32x2->bf16x2)
//   - symmetric halo offset -8: stage items are 8 px = aligned float4 global loads
//     + ds_write_b128; NO zero pass (interior margins are real pixels; cols>=48
//     are never read). Conv offset folded into band: Band[i][k] = g[k-i-3].
//   - h-pass: A = raw rows, B = band; D (C-layout) writes col-major H via b64.
//   - v-pass: A = band, B = H cols; SSIM math on fp32 acc, block reduce.
// 40 mfma/block; stage VALU ~5x lower than v4.

#define IMG 512
#define NPIX (16LL * 3 * 512 * 512)
#define NBLK (16 * 16 * 48)
#define RP 56   /* raw row pitch (shorts): mult 8 -> aligned b128; 28dw stride -> 2-way banks */
#define HP 56   /* hbuf col pitch (shorts) */

typedef short v8s __attribute__((ext_vector_type(8)));   // 8 x bf16 (4 VGPRs)
typedef float v4f __attribute__((ext_vector_type(4)));   // MFMA accumulator
typedef __bf16 bf2 __attribute__((ext_vector_type(2)));
typedef float f2  __attribute__((ext_vector_type(2)));

__device__ __forceinline__ int cvtpk(float lo, float hi) {   // -> v_cvt_pk_bf16_f32
    f2 f; f.x = lo; f.y = hi;
    bf2 r = __builtin_convertvector(f, bf2);
    return __builtin_bit_cast(int, r);
}
__device__ __forceinline__ unsigned f2bf(float f) {          // scalar fallback (setup only)
    unsigned u = __float_as_uint(f);
    return (u + 0x7FFFu + ((u >> 16) & 1u)) >> 16;
}

template <bool EDGE>
__device__ __forceinline__ void stage_tile(
    const float* __restrict__ p1, const float* __restrict__ p2,
    int tx0, int ty0, int tid, short (*raw)[48][RP])
{
    // 48 rows x 6 groups of 8 px; gr = ty0-8+row, gc = tx0-8+8*grp (4-aligned).
    for (int idx = tid; idx < 48 * 6; idx += 256) {
        const int row = idx / 6;
        const int grp = idx - row * 6;
        const int gr  = ty0 - 8 + row;
        const int gc  = tx0 - 8 + grp * 8;
        float4 a0, a1, b0, b1;
        if (!EDGE) {
            const size_t o = (size_t)gr * IMG + gc;
            a0 = *(const float4*)(p1 + o);
            a1 = *(const float4*)(p1 + o + 4);
            b0 = *(const float4*)(p2 + o);
            b1 = *(const float4*)(p2 + o + 4);
        } else {
            float4 z; z.x = z.y = z.z = z.w = 0.f;
            a0 = a1 = b0 = b1 = z;
            if ((unsigned)gr < IMG) {
                const float* r1 = p1 + (size_t)gr * IMG;
                const float* r2 = p2 + (size_t)gr * IMG;
                if ((unsigned)gc < IMG)       { a0 = *(const float4*)(r1 + gc);     b0 = *(const float4*)(r2 + gc); }
                if ((unsigned)(gc + 4) < IMG) { a1 = *(const float4*)(r1 + gc + 4); b1 = *(const float4*)(r2 + gc + 4); }
            }
        }
        const int c = grp * 8;
        int4 w;
        w.x = cvtpk(a0.x, a0.y); w.y = cvtpk(a0.z, a0.w);
        w.z = cvtpk(a1.x, a1.y); w.w = cvtpk(a1.z, a1.w);
        *(int4*)&raw[0][row][c] = w;
        w.x = cvtpk(b0.x, b0.y); w.y = cvtpk(b0.z, b0.w);
        w.z = cvtpk(b1.x, b1.y); w.w = cvtpk(b1.z, b1.w);
        *(int4*)&raw[1][row][c] = w;
        w.x = cvtpk(fmaf(a0.x, a0.x, b0.x * b0.x), fmaf(a0.y, a0.y, b0.y * b0.y));
        w.y = cvtpk(fmaf(a0.z, a0.z, b0.z * b0.z), fmaf(a0.w, a0.w, b0.w * b0.w));
        w.z = cvtpk(fmaf(a1.x, a1.x, b1.x * b1.x), fmaf(a1.y, a1.y, b1.y * b1.y));
        w.w = cvtpk(fmaf(a1.z, a1.z, b1.z * b1.z), fmaf(a1.w, a1.w, b1.w * b1.w));
        *(int4*)&raw[2][row][c] = w;
        w.x = cvtpk(a0.x * b0.x, a0.y * b0.y);
        w.y = cvtpk(a0.z * b0.z, a0.w * b0.w);
        w.z = cvtpk(a1.x * b1.x, a1.y * b1.y);
        w.w = cvtpk(a1.z * b1.z, a1.w * b1.w);
        *(int4*)&raw[3][row][c] = w;
    }
}

__global__ __launch_bounds__(256, 4) void ssim_kernel(
    const float* __restrict__ img1,
    const float* __restrict__ img2,
    const float* __restrict__ win,
    float* __restrict__ partial)
{
    __shared__ __align__(16) short raw [4][48][RP];  // 21504 B row-major, gr = ty0-8+ri
    __shared__ __align__(16) short hbuf[4][32][HP];  // 14336 B col-major [col][ri]
    __shared__ float sg[12];
    __shared__ float red[4];

    const int tid  = threadIdx.x;
    const int lane = tid & 63;
    const int wave = tid >> 6;
    const int lm   = lane & 15;
    const int quad = lane >> 4;

    const int bx = blockIdx.x, by = blockIdx.y, z = blockIdx.z;
    const int tx0 = bx * 32, ty0 = by * 32;

    if (tid < 12) sg[tid] = (tid < 11) ? win[55 + tid] * rsqrtf(win[60]) : 0.f;

    const size_t zoff = (size_t)z * IMG * IMG;
    const float* p1 = img1 + zoff;
    const float* p2 = img2 + zoff;

    const bool edge = (bx == 0) | (bx == 15) | (by == 0) | (by == 15);
    if (!edge) stage_tile<false>(p1, p2, tx0, ty0, tid, raw);
    else       stage_tile<true >(p1, p2, tx0, ty0, tid, raw);
    __syncthreads();

    // Band fragment (A- and B-role identical): value g[k - i - 3],
    // i = lane&15, k = quad*8 + j; sg[11] = 0 sentinel.
    v8s band;
    #pragma unroll
    for (int j = 0; j < 8; ++j) {
        int t  = quad * 8 + j - lm - 3;
        int tc = ((unsigned)t > 10u) ? 11 : t;
        band[j] = (short)f2bf(sg[tc]);
    }

    // ---- h-pass: 24 mfma (3 row-tiles x 2 col-tiles x 4 planes), 6/wave ----
    const v4f zacc = {0.f, 0.f, 0.f, 0.f};
    #pragma unroll
    for (int i = 0; i < 6; ++i) {
        const int id    = wave * 6 + i;
        const int plane = id & 3;
        const int s     = id >> 2;                   // 0..5
        const int r0    = (s < 3 ? s : s - 3) * 16;  // raw row tile {0,16,32}
        const int c0    = (s < 3 ? 0 : 16);          // out col tile
        const v8s a = *(const v8s*)&raw[plane][r0 + lm][c0 + quad * 8];
        const v4f acc = __builtin_amdgcn_mfma_f32_16x16x32_bf16(a, band, zacc, 0, 0, 0);
        int2 w2;
        w2.x = cvtpk(acc[0], acc[1]);
        w2.y = cvtpk(acc[2], acc[3]);
        *(int2*)&hbuf[plane][c0 + lm][r0 + quad * 4] = w2;
    }
    __syncthreads();

    // ---- v-pass: wave -> one 16x16 out tile, 4 plane-mfmas ----
    const int r0v = (wave & 1) * 16;
    const int c0v = (wave >> 1) * 16;
    v4f acc[4];
    #pragma unroll
    for (int p = 0; p < 4; ++p) {
        const v8s hf = *(const v8s*)&hbuf[p][c0v + lm][r0v + quad * 8];
        acc[p] = __builtin_amdgcn_mfma_f32_16x16x32_bf16(band, hf, zacc, 0, 0, 0);
    }

    const float C1c = 1e-4f;   // 0.01^2
    const float C2c = 9e-4f;   // 0.03^2
    float vsum = 0.f;
    #pragma unroll
    for (int r = 0; r < 4; ++r) {
        const float m1 = acc[0][r], m2 = acc[1][r];
        const float es = acc[2][r], ex = acc[3][r];
        const float m1s = m1 * m1, m2s = m2 * m2, m12 = m1 * m2;
        const float sig = es - m1s - m2s;            // sig1_sq + sig2_sq
        const float s12 = ex - m12;
        const float num = (2.f * m12 + C1c) * (2.f * s12 + C2c);
        const float den = (m1s + m2s + C1c) * (sig + C2c);
        vsum += num * __builtin_amdgcn_rcpf(den);
    }

    #pragma unroll
    for (int off = 32; off > 0; off >>= 1)
        vsum += __shfl_down(vsum, off, 64);
    if (lane == 0) red[wave] = vsum;
    __syncthreads();
    if (tid == 0) {
        const int bidx = (z * (int)gridDim.y + by) * (int)gridDim.x + bx;
        partial[bidx] = red[0] + red[1] + red[2] + red[3];
    }
}

__global__ __launch_bounds__(256) void finalize_kernel(
    const float* __restrict__ partial, float* __restrict__ out)
{
    __shared__ float red[4];
    const float4* p4 = (const float4*)partial;
    float s = 0.f;
    for (int i = threadIdx.x; i < NBLK / 4; i += 256) {
        float4 t = p4[i];
        s += (t.x + t.y) + (t.z + t.w);
    }
    #pragma unroll
    for (int off = 32; off > 0; off >>= 1)
        s += __shfl_down(s, off, 64);
    if ((threadIdx.x & 63) == 0) red[threadIdx.x >> 6] = s;
    __syncthreads();
    if (threadIdx.x == 0)
        out[0] = 1.0f - (red[0] + red[1] + red[2] + red[3]) / (float)NPIX;
}

extern "C" void kernel_launch(void* const* d_in, const int* in_sizes, int n_in,
                              void* d_out, int out_size, void* d_ws, size_t ws_size,
                              hipStream_t stream) {
    const float* img1 = (const float*)d_in[0];
    const float* img2 = (const float*)d_in[1];
    const float* win  = (const float*)d_in[2];
    float* partialb = (float*)d_ws;  // NBLK floats; every slot written each call

    dim3 grid(IMG / 32, IMG / 32, 48);
    ssim_kernel<<<grid, dim3(256), 0, stream>>>(img1, img2, win, partialb);
    finalize_kernel<<<1, dim3(256), 0, stream>>>(partialb, (float*)d_out);
}

// Round 6
// 143.658 us; speedup vs baseline: 1.1825x; 1.0529x over previous
//
#include <hip/hip_runtime.h>

// SSIM fused, v6: MFMA band-matmul conv, no raw-plane LDS.
//   h-pass: each lane loads its A-fragment (8 consecutive px per image) straight
//           from global (2x float4 per image), forms the 4 quantity planes
//           {x1, x2, x1^2+x2^2, x1*x2} in registers, 4 plane-MFMAs per spatial
//           tile. D (C-layout) -> col-major bf16 H planes in LDS (b64 writes).
//   v-pass: A = band, B = H cols (aligned ds_read_b128), SSIM on fp32 acc,
//           block reduce -> per-block partial.
// 32x64 output tile / block: 12 h-spatial tiles (wave = col-tile) + 8 v-tiles,
// 80 mfma / 2048 px. LDS = hbuf only (28.7 KB -> 5 blocks/CU). Band built via
// __shfl (no LDS, no init barrier): Band[i][k] = g[k-i-3], halo offset -8.
// Only 2 barriers per block; one global->register->MFMA phase, no staging.

#define IMG 512
#define NPIX (16LL * 3 * 512 * 512)
#define NBLK (8 * 16 * 48)   /* 6144 blocks -> 24 KB of partials in d_ws */
#define HP 56                /* hbuf per-col row pitch (shorts): 112 B -> 16B-aligned b128 */

typedef short v8s __attribute__((ext_vector_type(8)));   // 8 x bf16 (4 VGPRs)
typedef float v4f __attribute__((ext_vector_type(4)));   // MFMA accumulator
typedef __bf16 bf2 __attribute__((ext_vector_type(2)));
typedef float f2  __attribute__((ext_vector_type(2)));

__device__ __forceinline__ int cvtpk(float lo, float hi) {   // v_cvt_pk_bf16_f32
    f2 f; f.x = lo; f.y = hi;
    bf2 r = __builtin_convertvector(f, bf2);
    return __builtin_bit_cast(int, r);
}
__device__ __forceinline__ unsigned f2bf(float f) {
    unsigned u = __float_as_uint(f);
    return (u + 0x7FFFu + ((u >> 16) & 1u)) >> 16;
}

template <bool EDGE>
__device__ __forceinline__ void hpass(
    const float* __restrict__ p1, const float* __restrict__ p2,
    int tx0, int ty0, int lm, int quad, int ct, v8s band,
    short (*hbuf)[64][HP])
{
    const v4f zacc = {0.f, 0.f, 0.f, 0.f};
    #pragma unroll
    for (int rt = 0; rt < 3; ++rt) {
        const int grow = ty0 - 8 + rt * 16 + lm;        // raw pixel row
        const int gcol = tx0 - 8 + ct * 16 + quad * 8;  // raw pixel col (4-aligned)
        float4 a0, a1, b0, b1;
        if (!EDGE) {
            const float* r1 = p1 + (size_t)grow * IMG + gcol;
            const float* r2 = p2 + (size_t)grow * IMG + gcol;
            a0 = *(const float4*)r1;       a1 = *(const float4*)(r1 + 4);
            b0 = *(const float4*)r2;       b1 = *(const float4*)(r2 + 4);
        } else {
            float4 z4; z4.x = z4.y = z4.z = z4.w = 0.f;
            a0 = a1 = b0 = b1 = z4;
            if ((unsigned)grow < IMG) {
                const float* r1 = p1 + (size_t)grow * IMG;
                const float* r2 = p2 + (size_t)grow * IMG;
                if ((unsigned)gcol < IMG) {
                    a0 = *(const float4*)(r1 + gcol);
                    b0 = *(const float4*)(r2 + gcol);
                }
                if ((unsigned)(gcol + 4) < IMG) {
                    a1 = *(const float4*)(r1 + gcol + 4);
                    b1 = *(const float4*)(r2 + gcol + 4);
                }
            }
        }
        v8s A[4];
        int4 w;
        w.x = cvtpk(a0.x, a0.y); w.y = cvtpk(a0.z, a0.w);
        w.z = cvtpk(a1.x, a1.y); w.w = cvtpk(a1.z, a1.w);
        A[0] = __builtin_bit_cast(v8s, w);
        w.x = cvtpk(b0.x, b0.y); w.y = cvtpk(b0.z, b0.w);
        w.z = cvtpk(b1.x, b1.y); w.w = cvtpk(b1.z, b1.w);
        A[1] = __builtin_bit_cast(v8s, w);
        w.x = cvtpk(fmaf(a0.x, a0.x, b0.x * b0.x), fmaf(a0.y, a0.y, b0.y * b0.y));
        w.y = cvtpk(fmaf(a0.z, a0.z, b0.z * b0.z), fmaf(a0.w, a0.w, b0.w * b0.w));
        w.z = cvtpk(fmaf(a1.x, a1.x, b1.x * b1.x), fmaf(a1.y, a1.y, b1.y * b1.y));
        w.w = cvtpk(fmaf(a1.z, a1.z, b1.z * b1.z), fmaf(a1.w, a1.w, b1.w * b1.w));
        A[2] = __builtin_bit_cast(v8s, w);
        w.x = cvtpk(a0.x * b0.x, a0.y * b0.y);
        w.y = cvtpk(a0.z * b0.z, a0.w * b0.w);
        w.z = cvtpk(a1.x * b1.x, a1.y * b1.y);
        w.w = cvtpk(a1.z * b1.z, a1.w * b1.w);
        A[3] = __builtin_bit_cast(v8s, w);

        #pragma unroll
        for (int p = 0; p < 4; ++p) {
            const v4f acc = __builtin_amdgcn_mfma_f32_16x16x32_bf16(A[p], band, zacc, 0, 0, 0);
            // D: col n = lm (out col within col-tile), rows rt*16 + quad*4 + reg.
            int2 w2;
            w2.x = cvtpk(acc[0], acc[1]);
            w2.y = cvtpk(acc[2], acc[3]);
            *(int2*)&hbuf[p][ct * 16 + lm][rt * 16 + quad * 4] = w2;
        }
    }
}

__global__ __launch_bounds__(256, 5) void ssim_kernel(
    const float* __restrict__ img1,
    const float* __restrict__ img2,
    const float* __restrict__ win,
    float* __restrict__ partial)
{
    __shared__ __align__(16) short hbuf[4][64][HP];  // 28672 B, col-major [plane][col][hrow]
    __shared__ float red[4];

    const int tid  = threadIdx.x;
    const int lane = tid & 63;
    const int wave = tid >> 6;
    const int lm   = lane & 15;
    const int quad = lane >> 4;

    const int bx = blockIdx.x, by = blockIdx.y, z = blockIdx.z;
    const int tx0 = bx * 64, ty0 = by * 32;

    // Band fragment via shuffle (no LDS, no barrier): value g[k-i-3],
    // i = lane&15, k = quad*8+j; lanes >= 11 hold 0 -> sentinel lane 11.
    float gl = 0.f;
    if (lane < 11) gl = win[55 + lane] * rsqrtf(win[60]);
    v8s band;
    #pragma unroll
    for (int j = 0; j < 8; ++j) {
        const int t  = quad * 8 + j - lm - 3;
        const int tc = ((unsigned)t > 10u) ? 11 : t;
        band[j] = (short)f2bf(__shfl(gl, tc));
    }

    const size_t zoff = (size_t)z * IMG * IMG;
    const float* p1 = img1 + zoff;
    const float* p2 = img2 + zoff;

    // ---- h-pass: wave = col-tile (ct = wave), 3 row-tiles, 12 mfma/wave ----
    const bool interior = (bx > 0) & (bx < 7) & (by > 0) & (by < 15);
    if (interior) hpass<false>(p1, p2, tx0, ty0, lm, quad, wave, band, hbuf);
    else          hpass<true >(p1, p2, tx0, ty0, lm, quad, wave, band, hbuf);
    __syncthreads();

    // ---- v-pass: wave = out col-tile, 2 row-tiles x 4 planes = 8 mfma ----
    const v4f zacc = {0.f, 0.f, 0.f, 0.f};
    const float C1c = 1e-4f;   // 0.01^2
    const float C2c = 9e-4f;   // 0.03^2
    const int c0v = wave * 16;
    float vsum = 0.f;
    #pragma unroll
    for (int t2 = 0; t2 < 2; ++t2) {
        const int r0v = t2 * 16;
        v4f acc[4];
        #pragma unroll
        for (int p = 0; p < 4; ++p) {
            const v8s hf = *(const v8s*)&hbuf[p][c0v + lm][r0v + quad * 8];
            acc[p] = __builtin_amdgcn_mfma_f32_16x16x32_bf16(band, hf, zacc, 0, 0, 0);
        }
        #pragma unroll
        for (int r = 0; r < 4; ++r) {
            const float m1 = acc[0][r], m2 = acc[1][r];
            const float es = acc[2][r], ex = acc[3][r];
            const float m1s = m1 * m1, m2s = m2 * m2, m12 = m1 * m2;
            const float sig = es - m1s - m2s;        // sig1_sq + sig2_sq
            const float s12 = ex - m12;
            const float num = (2.f * m12 + C1c) * (2.f * s12 + C2c);
            const float den = (m1s + m2s + C1c) * (sig + C2c);
            vsum += num * __builtin_amdgcn_rcpf(den);
        }
    }

    // ---- block reduction -> per-block partial ----
    #pragma unroll
    for (int off = 32; off > 0; off >>= 1)
        vsum += __shfl_down(vsum, off, 64);
    if (lane == 0) red[wave] = vsum;
    __syncthreads();
    if (tid == 0) {
        const int bidx = (z * (int)gridDim.y + by) * (int)gridDim.x + bx;
        partial[bidx] = red[0] + red[1] + red[2] + red[3];
    }
}

__global__ __launch_bounds__(512) void finalize_kernel(
    const float* __restrict__ partial, float* __restrict__ out)
{
    __shared__ float red[8];
    const float4* p4 = (const float4*)partial;
    float s = 0.f;
    for (int i = threadIdx.x; i < NBLK / 4; i += 512) {   // 3 iterations
        float4 t = p4[i];
        s += (t.x + t.y) + (t.z + t.w);
    }
    #pragma unroll
    for (int off = 32; off > 0; off >>= 1)
        s += __shfl_down(s, off, 64);
    if ((threadIdx.x & 63) == 0) red[threadIdx.x >> 6] = s;
    __syncthreads();
    if (threadIdx.x == 0) {
        float t = 0.f;
        #pragma unroll
        for (int i = 0; i < 8; ++i) t += red[i];
        out[0] = 1.0f - t / (float)NPIX;
    }
}

extern "C" void kernel_launch(void* const* d_in, const int* in_sizes, int n_in,
                              void* d_out, int out_size, void* d_ws, size_t ws_size,
                              hipStream_t stream) {
    const float* img1 = (const float*)d_in[0];
    const float* img2 = (const float*)d_in[1];
    const float* win  = (const float*)d_in[2];
    float* partialb = (float*)d_ws;  // NBLK floats; every slot written each call

    dim3 grid(IMG / 64, IMG / 32, 48);
    ssim_kernel<<<grid, dim3(256), 0, stream>>>(img1, img2, win, partialb);
    finalize_kernel<<<1, dim3(512), 0, stream>>>(partialb, (float*)d_out);
}